// Round 10
// baseline (70.060 us; speedup 1.0000x reference)
//
#include <hip/hip_runtime.h>
#include <stdint.h>

// Problem constants (match reference)
#define BB 16384
#define SS 20
#define DD 128
#define EPSV 1e-5f

// R10: one wave = 1 batch row; each lane owns d0=2*lane, d0+1. The ONLY
// persistent per-lane state is x_norm packed as f16 s-pairs:
//   xq0[10] (elem d0, s-pairs), xq1[10] (elem d0+1)  -> 20 VGPRs.
// Goal: total VGPR <= 64 -> 8 waves/SIMD (R5..R9 all sat at the 4-waves
// residency granule with 80-128 VGPR and all landed ~57-59 us; this tests
// the latency-bound-at-fixed-residency theory).
// Conv taps +-1,+-2,+-4: one ds_bpermute of a packed reg fetches a
// neighbor's TWO s-rows -> 8 bpermutes per t-PAIR (80 DS/wave, half of R9).
// Gate: v_dot2_f32_f16 on the same packed regs (f32 accumulate).
// Residual dot + pre-RMS stats stay f32 (computed before packing).
// No LDS tile, no barrier, no launch-bounds min-waves arg (R6 lesson).

typedef __fp16 half2_t __attribute__((ext_vector_type(2)));

#define BPERMU(addr, v) ((uint32_t)__builtin_amdgcn_ds_bpermute((addr), (int)(v)))

static __device__ __forceinline__ float lo16(uint32_t u) {
    return (float)__builtin_bit_cast(half2_t, u)[0];
}
static __device__ __forceinline__ float hi16(uint32_t u) {
    return (float)__builtin_bit_cast(half2_t, u)[1];
}
static __device__ __forceinline__ uint32_t pk16(float a, float b) {
    return __builtin_bit_cast(uint32_t, __builtin_amdgcn_cvt_pkrtz(a, b));
}
static __device__ __forceinline__ float fdot2f(uint32_t a, uint32_t b, float c) {
    return __builtin_amdgcn_fdot2(__builtin_bit_cast(half2_t, a),
                                  __builtin_bit_cast(half2_t, b), c, false);
}

// ---- prep: pack gate_w [20][20] f32 -> [20][10] f16x2 in ws ----
__global__ void pack_gate_kernel(const float* __restrict__ gate_w,
                                 uint32_t*    __restrict__ ws) {
    const int i = threadIdx.x;            // single block of 256
    if (i < SS * (SS / 2)) {
        const int t = i / (SS / 2), p = i % (SS / 2);
        ws[i] = pk16(gate_w[t * SS + 2 * p], gate_w[t * SS + 2 * p + 1]);
    }
}

// One sub-iteration t (EX = lo16 or hi16 selecting the s within the pair).
#define ITER(t, EX)                                                          \
  {                                                                          \
    /* gate row t: 10+10 fdot2, f32 accumulate */                            \
    float g0 = gate_b[t]; float g1 = g0;                                     \
    _Pragma("unroll")                                                        \
    for (int q = 0; q < SS/2; ++q) {                                         \
      const uint32_t hw = gw_pk[(t) * (SS/2) + q];                           \
      g0 = fdot2f(xq0[q], hw, g0);                                           \
      g1 = fdot2f(xq1[q], hw, g1);                                           \
    }                                                                        \
    /* conv taps from packed halves */                                       \
    const float Ae0 = EX(A0), Ae1 = EX(A1);                                  \
    const float Be0 = EX(B0), Be1 = EX(B1);                                  \
    const float Ce0 = EX(C0), Ce1 = EX(C1);                                  \
    const float De0 = EX(D0), De1 = EX(D1);                                  \
    const float Oe0 = EX(xq0[(t) >> 1]), Oe1 = EX(xq1[(t) >> 1]);            \
    const float wa0 = w0[(t)*3+0], wa2 = w0[(t)*3+2];                        \
    const float wb0 = w1[(t)*3+0], wb2 = w1[(t)*3+2];                        \
    const float wc0 = w2[(t)*3+0], wc2 = w2[(t)*3+2];                        \
    const float cw   = w0[(t)*3+1] + w1[(t)*3+1] + w2[(t)*3+1];              \
    const float bias = b0[t] + b1[t] + b2[t];                                \
    float xd0 = bias;                                                        \
    xd0 = fmaf(wc0, Ae0, xd0);   /* d-4 */                                   \
    xd0 = fmaf(wb0, Be0, xd0);   /* d-2 */                                   \
    xd0 = fmaf(wa0, Be1, xd0);   /* d-1 */                                   \
    xd0 = fmaf(cw,  Oe0, xd0);   /* d   */                                   \
    xd0 = fmaf(wa2, Oe1, xd0);   /* d+1 */                                   \
    xd0 = fmaf(wb2, Ce0, xd0);   /* d+2 */                                   \
    xd0 = fmaf(wc2, De0, xd0);   /* d+4 */                                   \
    float xd1 = bias;                                                        \
    xd1 = fmaf(wc0, Ae1, xd1);   /* d-4 */                                   \
    xd1 = fmaf(wb0, Be1, xd1);   /* d-2 */                                   \
    xd1 = fmaf(wa0, Oe0, xd1);   /* d-1 */                                   \
    xd1 = fmaf(cw,  Oe1, xd1);   /* d   */                                   \
    xd1 = fmaf(wa2, Ce0, xd1);   /* d+1 */                                   \
    xd1 = fmaf(wb2, Ce1, xd1);   /* d+2 */                                   \
    xd1 = fmaf(wc2, De1, xd1);   /* d+4 */                                   \
    const float pl = post_w[t] * logit_w[t];                                 \
    const float h0 = xd0 * (g0 * __builtin_amdgcn_rcpf(1.f + __expf(-g0)));  \
    const float h1 = xd1 * (g1 * __builtin_amdgcn_rcpf(1.f + __expf(-g1)));  \
    m20 = fmaf(h0, h0, m20);                                                 \
    m21 = fmaf(h1, h1, m21);                                                 \
    ac0 = fmaf(h0, pl, ac0);                                                 \
    ac1 = fmaf(h1, pl, ac1);                                                 \
  }

__global__ __launch_bounds__(256) void fused_mdt_kernel(
    const int*      __restrict__ tokens,   // [B,S]
    const float*    __restrict__ emb,      // [V,D] (6 KB, cache-resident)
    const float*    __restrict__ pre_w,    // [S]
    const float*    __restrict__ w0, const float* __restrict__ b0,
    const float*    __restrict__ w1, const float* __restrict__ b1,
    const float*    __restrict__ w2, const float* __restrict__ b2,
    const uint32_t* __restrict__ gw_pk,    // [S][S/2] f16x2 (from prep)
    const float*    __restrict__ gate_b,   // [S]
    const float*    __restrict__ post_w,   // [S]
    const float*    __restrict__ logit_w,  // [1,S,1] -> flat [S]
    float*          __restrict__ out)      // [B,1,D] -> flat [B*D]
{
    const int tid  = threadIdx.x;
    const int lane = tid & 63;             // one row per wave
    const int b    = __builtin_amdgcn_readfirstlane(blockIdx.x * 4 + (tid >> 6));
    const int d0   = lane << 1;

    // edge masks ('same' zero padding) + bpermute addresses
    const bool eL1 = (lane == 0);
    const bool eL2 = (lane <  2);
    const bool eR1 = (lane == 63);
    const bool eR2 = (lane >= 62);
    const int aL1 = (lane - 1) << 2;
    const int aL2 = (lane - 2) << 2;
    const int aR1 = (lane + 1) << 2;
    const int aR2 = (lane + 2) << 2;

    // ---- prologue: gather, f32 stats, normalize, pack to f16 pairs ----
    uint32_t xq0[SS/2], xq1[SS/2];
    float a10, a11;
    {
        float x0[SS], x1[SS];
        {
            int tok[SS];
            const int4* t4 = reinterpret_cast<const int4*>(tokens + b * SS);
            #pragma unroll
            for (int i = 0; i < 5; ++i) {
                int4 v = t4[i];
                tok[4*i+0] = v.x; tok[4*i+1] = v.y;
                tok[4*i+2] = v.z; tok[4*i+3] = v.w;
            }
            #pragma unroll
            for (int s = 0; s < SS; ++s) {
                const float2 v = *reinterpret_cast<const float2*>(emb + tok[s] * DD + d0);
                x0[s] = v.x; x1[s] = v.y;
            }
        }
        float ms0 = 0.f, ms1 = 0.f;
        a10 = 0.f; a11 = 0.f;
        #pragma unroll
        for (int s = 0; s < SS; ++s) {
            ms0 = fmaf(x0[s], x0[s], ms0);
            ms1 = fmaf(x1[s], x1[s], ms1);
            const float lw = logit_w[s];
            a10 = fmaf(x0[s], lw, a10);
            a11 = fmaf(x1[s], lw, a11);
        }
        const float r0 = rsqrtf(ms0 * (1.f/SS) + EPSV);
        const float r1 = rsqrtf(ms1 * (1.f/SS) + EPSV);
        #pragma unroll
        for (int p = 0; p < SS/2; ++p) {
            const float pwA = pre_w[2*p], pwB = pre_w[2*p+1];
            xq0[p] = pk16(x0[2*p] * (r0 * pwA), x0[2*p+1] * (r0 * pwB));
            xq1[p] = pk16(x1[2*p] * (r1 * pwA), x1[2*p+1] * (r1 * pwB));
        }
    }   // x0/x1/tok die here: persistent state = 20 packed regs + 6 scalars

    // ---- main loop over s-pairs: 8 bpermutes serve rows 2p and 2p+1 ----
    float m20 = 0.f, m21 = 0.f, ac0 = 0.f, ac1 = 0.f;
    #pragma unroll
    for (int p = 0; p < SS/2; ++p) {
        uint32_t A0 = BPERMU(aL2, xq0[p]), A1 = BPERMU(aL2, xq1[p]);  // lane-2
        uint32_t B0 = BPERMU(aL1, xq0[p]), B1 = BPERMU(aL1, xq1[p]);  // lane-1
        uint32_t C0 = BPERMU(aR1, xq0[p]), C1 = BPERMU(aR1, xq1[p]);  // lane+1
        uint32_t D0 = BPERMU(aR2, xq0[p]), D1 = BPERMU(aR2, xq1[p]);  // lane+2
        A0 = eL2 ? 0u : A0;  A1 = eL2 ? 0u : A1;
        B0 = eL1 ? 0u : B0;  B1 = eL1 ? 0u : B1;
        C0 = eR1 ? 0u : C0;  C1 = eR1 ? 0u : C1;
        D0 = eR2 ? 0u : D0;  D1 = eR2 ? 0u : D1;

        ITER(2*p,     lo16)
        ITER(2*p + 1, hi16)
    }

    const float q0 = rsqrtf(m20 * (1.f/SS) + EPSV);
    const float q1 = rsqrtf(m21 * (1.f/SS) + EPSV);

    float2 res;
    res.x = a10 + q0 * ac0;
    res.y = a11 + q1 * ac1;
    *reinterpret_cast<float2*>(out + b * DD + d0) = res;
}

extern "C" void kernel_launch(void* const* d_in, const int* in_sizes, int n_in,
                              void* d_out, int out_size, void* d_ws, size_t ws_size,
                              hipStream_t stream) {
    const int*   tokens  = (const int*)  d_in[0];
    // d_in[1] = number_log — unused by the reference
    const float* emb     = (const float*)d_in[2];
    const float* pre_w   = (const float*)d_in[3];
    const float* w0      = (const float*)d_in[4];
    const float* b0      = (const float*)d_in[5];
    const float* w1      = (const float*)d_in[6];
    const float* b1      = (const float*)d_in[7];
    const float* w2      = (const float*)d_in[8];
    const float* b2      = (const float*)d_in[9];
    const float* gate_w  = (const float*)d_in[10];
    const float* gate_b  = (const float*)d_in[11];
    const float* post_w  = (const float*)d_in[12];
    const float* logit_w = (const float*)d_in[13];
    float*       out     = (float*)d_out;
    uint32_t*    ws      = (uint32_t*)d_ws;

    hipLaunchKernelGGL(pack_gate_kernel, dim3(1), dim3(256), 0, stream,
                       gate_w, ws);

    dim3 grid(BB / 4);   // 4 rows (4 waves) per 256-thread block
    dim3 block(256);
    hipLaunchKernelGGL(fused_mdt_kernel, grid, block, 0, stream,
                       tokens, emb, pre_w, w0, b0, w1, b1, w2, b2,
                       (const uint32_t*)ws, gate_b, post_w, logit_w, out);
}

// Round 11
// 57.726 us; speedup vs baseline: 1.2136x; 1.2136x over previous
//
#include <hip/hip_runtime.h>
#include <stdint.h>

// Problem constants (match reference)
#define BB 16384
#define SS 20
#define DD 128
#define EPSV 1e-5f

// R11 = R9's dataflow with half the register state.
// One wave = 2 batch rows; 32 lanes/row; lane owns 4 consecutive d (d0=4*il).
// TWO-PASS prologue: pass A streams emb (L1-resident, 6 KB) for RMS stats
// storing NOTHING; pass B re-reads emb, normalizes, packs straight to f16
// s-pairs xq0..3[10] (40 VGPR) -- no f32 xn array ever lives (R9 kept both
// -> 128 VGPR -> 4 waves/SIMD; R10's 2d variant peaked in the prologue).
// sched_barrier(0) between passes stops the compiler hoisting pass-B loads
// (which would recreate the f32 arrays). Conv taps extracted from packed
// regs (R10-proven precision, absmax 3.9e-3). 8 bpermutes per s-pair serve
// both rows 2p,2p+1 (R9). Gate = fdot2 on packed regs. Full unroll (R9).
// No LDS tile, no barrier, no launch-bounds min-waves cap (R6 lesson).

typedef __fp16 half2_t __attribute__((ext_vector_type(2)));

#define BPERMU(addr, v) ((uint32_t)__builtin_amdgcn_ds_bpermute((addr), (int)(v)))

static __device__ __forceinline__ float lo16(uint32_t u) {
    return (float)__builtin_bit_cast(half2_t, u)[0];
}
static __device__ __forceinline__ float hi16(uint32_t u) {
    return (float)__builtin_bit_cast(half2_t, u)[1];
}
static __device__ __forceinline__ uint32_t pk16(float a, float b) {
    return __builtin_bit_cast(uint32_t, __builtin_amdgcn_cvt_pkrtz(a, b));
}
static __device__ __forceinline__ float fdot2f(uint32_t a, uint32_t b, float c) {
    return __builtin_amdgcn_fdot2(__builtin_bit_cast(half2_t, a),
                                  __builtin_bit_cast(half2_t, b), c, false);
}

// ---- prep: pack gate_w [20][20] f32 -> [20][10] f16x2 in ws ----
__global__ void pack_gate_kernel(const float* __restrict__ gate_w,
                                 uint32_t*    __restrict__ ws) {
    const int i = threadIdx.x;            // single block of 256
    if (i < SS * (SS / 2)) {
        const int t = i / (SS / 2), p = i % (SS / 2);
        ws[i] = pk16(gate_w[t * SS + 2 * p], gate_w[t * SS + 2 * p + 1]);
    }
}

// One t-iteration; EX = lo16/hi16 selects s within the pair p = t>>1.
// Uses: xq0..3, BL0..3/BR0..3 (masked bperm results), weights, accumulators.
#define ITER(t, EX)                                                          \
  {                                                                          \
    /* gate row t: 40 fdot2, f32 accumulate (covers bperm latency) */        \
    float g0 = gate_b[t]; float g1 = g0, g2 = g0, g3 = g0;                   \
    _Pragma("unroll")                                                        \
    for (int q = 0; q < SS/2; ++q) {                                         \
      const uint32_t hw = gw_pk[(t) * (SS/2) + q];                           \
      g0 = fdot2f(xq0[q], hw, g0);                                           \
      g1 = fdot2f(xq1[q], hw, g1);                                           \
      g2 = fdot2f(xq2[q], hw, g2);                                           \
      g3 = fdot2f(xq3[q], hw, g3);                                           \
    }                                                                        \
    /* tap extraction (12 cvt): halo d0-4+k / d0+4+k, own d0+k at s=t */     \
    const float HL0 = EX(BL0), HL1 = EX(BL1), HL2 = EX(BL2), HL3 = EX(BL3);  \
    const float HR0 = EX(BR0), HR1 = EX(BR1), HR2 = EX(BR2), HR3 = EX(BR3);  \
    const float O0 = EX(xq0[(t) >> 1]), O1 = EX(xq1[(t) >> 1]);              \
    const float O2 = EX(xq2[(t) >> 1]), O3 = EX(xq3[(t) >> 1]);              \
    const float wa0 = w0[(t)*3+0], wa2 = w0[(t)*3+2];   /* dil 1 */          \
    const float wb0 = w1[(t)*3+0], wb2 = w1[(t)*3+2];   /* dil 2 */          \
    const float wc0 = w2[(t)*3+0], wc2 = w2[(t)*3+2];   /* dil 4 */          \
    const float cw   = w0[(t)*3+1] + w1[(t)*3+1] + w2[(t)*3+1];              \
    const float bias = b0[t] + b1[t] + b2[t];                                \
    /* conv outputs j=0..3 (tap map verified R5/R9) */                       \
    float xd0 = bias;                                                        \
    xd0 = fmaf(wc0, HL0, xd0);                                               \
    xd0 = fmaf(wb0, HL2, xd0);                                               \
    xd0 = fmaf(wa0, HL3, xd0);                                               \
    xd0 = fmaf(cw,  O0,  xd0);                                               \
    xd0 = fmaf(wa2, O1,  xd0);                                               \
    xd0 = fmaf(wb2, O2,  xd0);                                               \
    xd0 = fmaf(wc2, HR0, xd0);                                               \
    float xd1 = bias;                                                        \
    xd1 = fmaf(wc0, HL1, xd1);                                               \
    xd1 = fmaf(wb0, HL3, xd1);                                               \
    xd1 = fmaf(wa0, O0,  xd1);                                               \
    xd1 = fmaf(cw,  O1,  xd1);                                               \
    xd1 = fmaf(wa2, O2,  xd1);                                               \
    xd1 = fmaf(wb2, O3,  xd1);                                               \
    xd1 = fmaf(wc2, HR1, xd1);                                               \
    float xd2 = bias;                                                        \
    xd2 = fmaf(wc0, HL2, xd2);                                               \
    xd2 = fmaf(wb0, O0,  xd2);                                               \
    xd2 = fmaf(wa0, O1,  xd2);                                               \
    xd2 = fmaf(cw,  O2,  xd2);                                               \
    xd2 = fmaf(wa2, O3,  xd2);                                               \
    xd2 = fmaf(wb2, HR0, xd2);                                               \
    xd2 = fmaf(wc2, HR2, xd2);                                               \
    float xd3 = bias;                                                        \
    xd3 = fmaf(wc0, HL3, xd3);                                               \
    xd3 = fmaf(wb0, O1,  xd3);                                               \
    xd3 = fmaf(wa0, O2,  xd3);                                               \
    xd3 = fmaf(cw,  O3,  xd3);                                               \
    xd3 = fmaf(wa2, HR0, xd3);                                               \
    xd3 = fmaf(wb2, HR1, xd3);                                               \
    xd3 = fmaf(wc2, HR3, xd3);                                               \
    const float pl = post_w[t] * logit_w[t];                                 \
    const float h0 = xd0 * (g0 * __builtin_amdgcn_rcpf(1.f + __expf(-g0)));  \
    const float h1 = xd1 * (g1 * __builtin_amdgcn_rcpf(1.f + __expf(-g1)));  \
    const float h2 = xd2 * (g2 * __builtin_amdgcn_rcpf(1.f + __expf(-g2)));  \
    const float h3 = xd3 * (g3 * __builtin_amdgcn_rcpf(1.f + __expf(-g3)));  \
    m20 = fmaf(h0, h0, m20); m21 = fmaf(h1, h1, m21);                        \
    m22 = fmaf(h2, h2, m22); m23 = fmaf(h3, h3, m23);                        \
    ac0 = fmaf(h0, pl, ac0); ac1 = fmaf(h1, pl, ac1);                        \
    ac2 = fmaf(h2, pl, ac2); ac3 = fmaf(h3, pl, ac3);                        \
  }

__global__ __launch_bounds__(256) void fused_mdt_kernel(
    const int*      __restrict__ tokens,   // [B,S]
    const float*    __restrict__ emb,      // [V,D] (6 KB, cache-resident)
    const float*    __restrict__ pre_w,    // [S]
    const float*    __restrict__ w0, const float* __restrict__ b0,
    const float*    __restrict__ w1, const float* __restrict__ b1,
    const float*    __restrict__ w2, const float* __restrict__ b2,
    const uint32_t* __restrict__ gw_pk,    // [S][S/2] f16x2 (from prep)
    const float*    __restrict__ gate_b,   // [S]
    const float*    __restrict__ post_w,   // [S]
    const float*    __restrict__ logit_w,  // [1,S,1] -> flat [S]
    float*          __restrict__ out)      // [B,1,D] -> flat [B*D]
{
    const int tid  = threadIdx.x;
    const int lane = tid & 63;               // lane within wave
    const int il   = lane & 31;              // lane within row
    const int b    = blockIdx.x * 8 + (tid >> 5);
    const int d0   = il << 2;

    const bool le = (il == 0);               // left row edge
    const bool re = (il == 31);              // right row edge
    const int  la = (lane - 1) << 2;         // bpermute: pull lane-1
    const int  ra = (lane + 1) << 2;         // pull lane+1 (wraps masked)

    const int4* t4 = reinterpret_cast<const int4*>(tokens + b * SS);

    // ---- pass A: stream emb for RMS stats + residual dot; store nothing ----
    float ms0=0.f, ms1=0.f, ms2=0.f, ms3=0.f;
    float a10=0.f, a11=0.f, a12=0.f, a13=0.f;
    {
        int tok[SS];
        #pragma unroll
        for (int i = 0; i < 5; ++i) {
            int4 v = t4[i];
            tok[4*i+0] = v.x; tok[4*i+1] = v.y;
            tok[4*i+2] = v.z; tok[4*i+3] = v.w;
        }
        #pragma unroll
        for (int s = 0; s < SS; ++s) {
            const float4 v = *reinterpret_cast<const float4*>(emb + tok[s] * DD + d0);
            ms0 = fmaf(v.x, v.x, ms0); ms1 = fmaf(v.y, v.y, ms1);
            ms2 = fmaf(v.z, v.z, ms2); ms3 = fmaf(v.w, v.w, ms3);
            const float lw = logit_w[s];
            a10 = fmaf(v.x, lw, a10); a11 = fmaf(v.y, lw, a11);
            a12 = fmaf(v.z, lw, a12); a13 = fmaf(v.w, lw, a13);
        }
    }
    const float r0 = rsqrtf(ms0 * (1.f/SS) + EPSV);
    const float r1 = rsqrtf(ms1 * (1.f/SS) + EPSV);
    const float r2 = rsqrtf(ms2 * (1.f/SS) + EPSV);
    const float r3 = rsqrtf(ms3 * (1.f/SS) + EPSV);

    // fence: pass-B loads must not hoist above pass A (would recreate x[] f32)
    __builtin_amdgcn_sched_barrier(0);

    // ---- pass B: re-read emb (L1-hot), normalize, pack f16 s-pairs ----
    uint32_t xq0[SS/2], xq1[SS/2], xq2[SS/2], xq3[SS/2];
    {
        int tok[SS];
        #pragma unroll
        for (int i = 0; i < 5; ++i) {
            int4 v = t4[i];
            tok[4*i+0] = v.x; tok[4*i+1] = v.y;
            tok[4*i+2] = v.z; tok[4*i+3] = v.w;
        }
        #pragma unroll
        for (int p = 0; p < SS/2; ++p) {
            const float4 va = *reinterpret_cast<const float4*>(emb + tok[2*p]   * DD + d0);
            const float4 vb = *reinterpret_cast<const float4*>(emb + tok[2*p+1] * DD + d0);
            const float wA = pre_w[2*p], wB = pre_w[2*p+1];
            xq0[p] = pk16(va.x * (r0 * wA), vb.x * (r0 * wB));
            xq1[p] = pk16(va.y * (r1 * wA), vb.y * (r1 * wB));
            xq2[p] = pk16(va.z * (r2 * wA), vb.z * (r2 * wB));
            xq3[p] = pk16(va.w * (r3 * wA), vb.w * (r3 * wB));
        }
    }

    __builtin_amdgcn_sched_barrier(0);

    // ---- main loop: 8 bpermutes per s-pair serve rows 2p and 2p+1 ----
    float m20=0.f, m21=0.f, m22=0.f, m23=0.f;
    float ac0=0.f, ac1=0.f, ac2=0.f, ac3=0.f;
    #pragma unroll
    for (int p = 0; p < SS/2; ++p) {
        uint32_t BL0 = BPERMU(la, xq0[p]), BL1 = BPERMU(la, xq1[p]);
        uint32_t BL2 = BPERMU(la, xq2[p]), BL3 = BPERMU(la, xq3[p]);
        uint32_t BR0 = BPERMU(ra, xq0[p]), BR1 = BPERMU(ra, xq1[p]);
        uint32_t BR2 = BPERMU(ra, xq2[p]), BR3 = BPERMU(ra, xq3[p]);
        BL0 = le ? 0u : BL0;  BL1 = le ? 0u : BL1;
        BL2 = le ? 0u : BL2;  BL3 = le ? 0u : BL3;
        BR0 = re ? 0u : BR0;  BR1 = re ? 0u : BR1;
        BR2 = re ? 0u : BR2;  BR3 = re ? 0u : BR3;

        ITER(2*p,     lo16)
        ITER(2*p + 1, hi16)
    }

    const float q0 = rsqrtf(m20 * (1.f/SS) + EPSV);
    const float q1 = rsqrtf(m21 * (1.f/SS) + EPSV);
    const float q2 = rsqrtf(m22 * (1.f/SS) + EPSV);
    const float q3 = rsqrtf(m23 * (1.f/SS) + EPSV);

    float4 res;
    res.x = a10 + q0 * ac0;
    res.y = a11 + q1 * ac1;
    res.z = a12 + q2 * ac2;
    res.w = a13 + q3 * ac3;
    *reinterpret_cast<float4*>(out + b * DD + d0) = res;
}

extern "C" void kernel_launch(void* const* d_in, const int* in_sizes, int n_in,
                              void* d_out, int out_size, void* d_ws, size_t ws_size,
                              hipStream_t stream) {
    const int*   tokens  = (const int*)  d_in[0];
    // d_in[1] = number_log — unused by the reference
    const float* emb     = (const float*)d_in[2];
    const float* pre_w   = (const float*)d_in[3];
    const float* w0      = (const float*)d_in[4];
    const float* b0      = (const float*)d_in[5];
    const float* w1      = (const float*)d_in[6];
    const float* b1      = (const float*)d_in[7];
    const float* w2      = (const float*)d_in[8];
    const float* b2      = (const float*)d_in[9];
    const float* gate_w  = (const float*)d_in[10];
    const float* gate_b  = (const float*)d_in[11];
    const float* post_w  = (const float*)d_in[12];
    const float* logit_w = (const float*)d_in[13];
    float*       out     = (float*)d_out;
    uint32_t*    ws      = (uint32_t*)d_ws;

    hipLaunchKernelGGL(pack_gate_kernel, dim3(1), dim3(256), 0, stream,
                       gate_w, ws);

    dim3 grid(BB / 8);   // 8 rows per 256-thread block -> 2048 blocks
    dim3 block(256);
    hipLaunchKernelGGL(fused_mdt_kernel, grid, block, 0, stream,
                       tokens, emb, pre_w, w0, b0, w1, b1, w2, b2,
                       (const uint32_t*)ws, gate_b, post_w, logit_w, out);
}